// Round 13
// baseline (1418.778 us; speedup 1.0000x reference)
//
#include <hip/hip_runtime.h>

#define N_NODES 50000
#define N_EDGES 800000
#define DIM     128
#define D4      32          // DIM/4 float4 groups
#define NLAYERS 3
#define NATOM   9
#define AVOC    64
#define NBOND   3
#define BVOC    8
#define BN_EPS  1e-5f
#define INVN    (1.0f / (float)N_NODES)

// ---------------------------------------------------------------------------
// Atom encoder: h[n][d] = sum_c atom_emb[c][x[n][c]][d]
// ---------------------------------------------------------------------------
__global__ __launch_bounds__(256) void atom_kernel(
    const int* __restrict__ x, const float* __restrict__ ae,
    float* __restrict__ h, int n_nodes)
{
    int tid  = threadIdx.x;
    int lane = tid & 31;
    int node = blockIdx.x * 8 + (tid >> 5);
    if (node >= n_nodes) return;
    const int* xr = x + node * NATOM;
    const float4* ae4 = (const float4*)ae;
    float4 acc = make_float4(0.f, 0.f, 0.f, 0.f);
#pragma unroll
    for (int c = 0; c < NATOM; c++) {
        int v = xr[c];
        float4 t = ae4[(c * AVOC + v) * D4 + lane];
        acc.x += t.x; acc.y += t.y; acc.z += t.z; acc.w += t.w;
    }
    ((float4*)h)[node * D4 + lane] = acc;
}

// ---------------------------------------------------------------------------
// CSR build: histogram -> hierarchical scan -> bucket fill (src+bond packed)
// ---------------------------------------------------------------------------
__global__ void hist_kernel(const int* __restrict__ dst, int* __restrict__ counts, int n)
{
    int e = blockIdx.x * blockDim.x + threadIdx.x;
    if (e < n) atomicAdd(&counts[dst[e]], 1);
}

__global__ __launch_bounds__(256) void scan1_kernel(
    const int* __restrict__ counts, int* __restrict__ incl,
    int* __restrict__ blk_sums, int n)
{
    __shared__ int sh[256];
    int tid = threadIdx.x;
    int i = blockIdx.x * 256 + tid;
    int v = (i < n) ? counts[i] : 0;
    sh[tid] = v;
    __syncthreads();
    for (int off = 1; off < 256; off <<= 1) {
        int t = (tid >= off) ? sh[tid - off] : 0;
        __syncthreads();
        sh[tid] += t;
        __syncthreads();
    }
    if (i < n) incl[i] = sh[tid];
    if (tid == 255) blk_sums[blockIdx.x] = sh[255];
}

__global__ __launch_bounds__(256) void scan2_kernel(int* __restrict__ blk_sums, int nblk)
{
    __shared__ int sh[256];
    int tid = threadIdx.x;
    int v = (tid < nblk) ? blk_sums[tid] : 0;
    sh[tid] = v;
    __syncthreads();
    for (int off = 1; off < 256; off <<= 1) {
        int t = (tid >= off) ? sh[tid - off] : 0;
        __syncthreads();
        sh[tid] += t;
        __syncthreads();
    }
    if (tid < nblk) blk_sums[tid] = sh[tid] - v;   // exclusive
}

__global__ __launch_bounds__(256) void scan3_kernel(
    const int* __restrict__ counts, const int* __restrict__ incl,
    const int* __restrict__ blk_sums, int* __restrict__ row_ptr,
    int* __restrict__ cursor, int n)
{
    int i = blockIdx.x * 256 + threadIdx.x;
    if (i >= n) return;
    int total = incl[i] + blk_sums[blockIdx.x];
    row_ptr[i + 1] = total;
    cursor[i] = total - counts[i];
    if (i == 0) row_ptr[0] = 0;
}

// fill: store src and packed bond indices at the CSR slot (kills one
// indirection level in agg: no edge_ids->src/edge_attr chase)
__global__ void fill_kernel(const int* __restrict__ dst, const int* __restrict__ src,
                            const int* __restrict__ edge_attr, int* __restrict__ cursor,
                            int* __restrict__ esrc, int* __restrict__ ebond, int n)
{
    int e = blockIdx.x * blockDim.x + threadIdx.x;
    if (e >= n) return;
    int p = atomicAdd(&cursor[dst[e]], 1);
    esrc[p] = src[e];
    const int* ea = edge_attr + e * 3;
    ebond[p] = ea[0] | (ea[1] << 8) | (ea[2] << 16);
}

// ---------------------------------------------------------------------------
// Edge aggregation (CSR, no float atomics). Optionally applies the previous
// layer's outer-BN (+ReLU) to its input on the fly (coefs from raw sums):
//   h_eff = BNIN ? relu(sc*zin + sf) : zin
//   z[n] = (1+eps)*h_eff[n] + sum_{e: dst==n} relu(h_eff[src] + bond_emb)
// ---------------------------------------------------------------------------
template <bool BNIN>
__global__ __launch_bounds__(256) void agg_kernel(
    const float* __restrict__ zin, const int* __restrict__ row_ptr,
    const int* __restrict__ esrc, const int* __restrict__ ebond,
    const float* __restrict__ bond_l, const float* __restrict__ epsp,
    const float* __restrict__ sum2p, const float* __restrict__ ssq2p,
    const float* __restrict__ gam, const float* __restrict__ bet,
    float* __restrict__ z, int n_nodes)
{
    __shared__ float4 bt[NBOND * BVOC * D4];   // 12 KB
    int tid = threadIdx.x;
    const float4* b4 = (const float4*)bond_l;
    for (int i = tid; i < NBOND * BVOC * D4; i += 256) bt[i] = b4[i];
    __syncthreads();

    int lane = tid & 31;
    int node = blockIdx.x * 8 + (tid >> 5);
    if (node >= n_nodes) return;

    // per-lane BN coefs for this lane's 4 columns
    float4 sc = make_float4(1.f, 1.f, 1.f, 1.f);
    float4 sf = make_float4(0.f, 0.f, 0.f, 0.f);
    if (BNIN) {
        float4 sm = ((const float4*)sum2p)[lane];
        float4 sq = ((const float4*)ssq2p)[lane];
        float4 g  = ((const float4*)gam)[lane];
        float4 b  = ((const float4*)bet)[lane];
        float mux = sm.x * INVN, muy = sm.y * INVN, muz = sm.z * INVN, muw = sm.w * INVN;
        float vx = fmaxf(sq.x * INVN - mux * mux, 0.f);
        float vy = fmaxf(sq.y * INVN - muy * muy, 0.f);
        float vz = fmaxf(sq.z * INVN - muz * muz, 0.f);
        float vw = fmaxf(sq.w * INVN - muw * muw, 0.f);
        sc.x = g.x * rsqrtf(vx + BN_EPS); sc.y = g.y * rsqrtf(vy + BN_EPS);
        sc.z = g.z * rsqrtf(vz + BN_EPS); sc.w = g.w * rsqrtf(vw + BN_EPS);
        sf.x = fmaf(-mux, sc.x, b.x); sf.y = fmaf(-muy, sc.y, b.y);
        sf.z = fmaf(-muz, sc.z, b.z); sf.w = fmaf(-muw, sc.w, b.w);
    }

    float eps = epsp[0];
    int j0 = row_ptr[node], j1 = row_ptr[node + 1];
    const float4* zin4 = (const float4*)zin;
    float4 acc = make_float4(0.f, 0.f, 0.f, 0.f);

#define HEFF(v) do { if (BNIN) { \
        (v).x = fmaxf(fmaf((v).x, sc.x, sf.x), 0.f); \
        (v).y = fmaxf(fmaf((v).y, sc.y, sf.y), 0.f); \
        (v).z = fmaxf(fmaf((v).z, sc.z, sf.z), 0.f); \
        (v).w = fmaxf(fmaf((v).w, sc.w, sf.w), 0.f); } } while (0)

    int j = j0;
    for (; j + 2 <= j1; j += 2) {
        int s0 = esrc[j],     bb0 = ebond[j];
        int s1 = esrc[j + 1], bb1 = ebond[j + 1];
        float4 h0 = zin4[(size_t)s0 * D4 + lane];
        float4 h1 = zin4[(size_t)s1 * D4 + lane];
        float4 a0 = bt[(bb0 & 255) * D4 + lane];
        float4 a1 = bt[(BVOC + ((bb0 >> 8) & 255)) * D4 + lane];
        float4 a2 = bt[(2 * BVOC + ((bb0 >> 16) & 255)) * D4 + lane];
        float4 c0 = bt[(bb1 & 255) * D4 + lane];
        float4 c1 = bt[(BVOC + ((bb1 >> 8) & 255)) * D4 + lane];
        float4 c2 = bt[(2 * BVOC + ((bb1 >> 16) & 255)) * D4 + lane];
        HEFF(h0); HEFF(h1);
        acc.x += fmaxf(h0.x + a0.x + a1.x + a2.x, 0.f) + fmaxf(h1.x + c0.x + c1.x + c2.x, 0.f);
        acc.y += fmaxf(h0.y + a0.y + a1.y + a2.y, 0.f) + fmaxf(h1.y + c0.y + c1.y + c2.y, 0.f);
        acc.z += fmaxf(h0.z + a0.z + a1.z + a2.z, 0.f) + fmaxf(h1.z + c0.z + c1.z + c2.z, 0.f);
        acc.w += fmaxf(h0.w + a0.w + a1.w + a2.w, 0.f) + fmaxf(h1.w + c0.w + c1.w + c2.w, 0.f);
    }
    if (j < j1) {
        int s0 = esrc[j], bb0 = ebond[j];
        float4 h0 = zin4[(size_t)s0 * D4 + lane];
        float4 a0 = bt[(bb0 & 255) * D4 + lane];
        float4 a1 = bt[(BVOC + ((bb0 >> 8) & 255)) * D4 + lane];
        float4 a2 = bt[(2 * BVOC + ((bb0 >> 16) & 255)) * D4 + lane];
        HEFF(h0);
        acc.x += fmaxf(h0.x + a0.x + a1.x + a2.x, 0.f);
        acc.y += fmaxf(h0.y + a0.y + a1.y + a2.y, 0.f);
        acc.z += fmaxf(h0.z + a0.z + a1.z + a2.z, 0.f);
        acc.w += fmaxf(h0.w + a0.w + a1.w + a2.w, 0.f);
    }

    float4 hn = zin4[(size_t)node * D4 + lane];
    HEFF(hn);
#undef HEFF
    float s1v = 1.f + eps;
    float4 o;
    o.x = fmaf(s1v, hn.x, acc.x);
    o.y = fmaf(s1v, hn.y, acc.y);
    o.z = fmaf(s1v, hn.z, acc.z);
    o.w = fmaf(s1v, hn.w, acc.w);
    ((float4*)z)[(size_t)node * D4 + lane] = o;
}

// ---------------------------------------------------------------------------
// GEMM + fused column-stats epilogue, retiled for occupancy:
//   32 rows/block, 256 threads (tx=col-group 0..31 x 4 cols, ty=0..7 x 4 rows),
//   W staged as two 64x128 k-panels (32 KB LDS) -> ~4-5 blocks/CU resident,
//   grid 1563 blocks (was 391).  Same fp32 FMA order as before (bitwise-equal
//   GEMM outputs); only the stats reduction tree shape changes.
// If BN: A_eff = relu(scale*A + shift), coefs computed inline from raw sums.
// ---------------------------------------------------------------------------
#define GROWS 32   // rows per block
template <bool BN>
__global__ __launch_bounds__(256, 4) void gemm_kernel(
    const float* __restrict__ A, const float* __restrict__ W,
    const float* __restrict__ bias,
    const float* __restrict__ sum_in, const float* __restrict__ ssq_in,
    const float* __restrict__ gam, const float* __restrict__ bet,
    float* __restrict__ sum_out, float* __restrict__ ssq_out,
    float* __restrict__ out, int nrows)
{
    __shared__ float Ws[64 * DIM];           // 32 KB k-panel (reused for stats)
    __shared__ float scs[DIM], shs[DIM];
    int tid = threadIdx.x;
    if (BN && tid < DIM) {
        float mu = sum_in[tid] * INVN;
        float var = fmaxf(ssq_in[tid] * INVN - mu * mu, 0.f);
        float sc = gam[tid] * rsqrtf(var + BN_EPS);
        scs[tid] = sc;
        shs[tid] = fmaf(-mu, sc, bet[tid]);
    }

    int tx = tid & 31;
    int ty = tid >> 5;                 // 0..7
    int row0 = blockIdx.x * GROWS + ty * 4;

    int ar[4];
#pragma unroll
    for (int r = 0; r < 4; r++) {
        int rr = row0 + r; if (rr > nrows - 1) rr = nrows - 1;
        ar[r] = rr * D4;
    }

    float4 acc[4];
#pragma unroll
    for (int r = 0; r < 4; r++) acc[r] = make_float4(0.f, 0.f, 0.f, 0.f);

    const float4* A4  = (const float4*)A;
    const float4* W4  = (const float4*)W;
    const float4* Ws4 = (const float4*)Ws;
    float4* WsS = (float4*)Ws;
    const float4* sc4p = (const float4*)scs;
    const float4* sh4p = (const float4*)shs;

    for (int p = 0; p < 2; ++p) {
        int kb = p * 64;
        __syncthreads();    // previous-panel readers done (also fences scs)
        for (int i = tid; i < 64 * D4; i += 256) WsS[i] = W4[kb * D4 + i];
        __syncthreads();
        for (int k = 0; k < 64; k += 4) {
            float4 b0 = Ws4[(k + 0) * D4 + tx];
            float4 b1 = Ws4[(k + 1) * D4 + tx];
            float4 b2 = Ws4[(k + 2) * D4 + tx];
            float4 b3 = Ws4[(k + 3) * D4 + tx];
            float4 sc, sf;
            if (BN) { sc = sc4p[(kb + k) >> 2]; sf = sh4p[(kb + k) >> 2]; }
#pragma unroll
            for (int r = 0; r < 4; r++) {
                float4 a = A4[ar[r] + ((kb + k) >> 2)];
                if (BN) {
                    a.x = fmaxf(fmaf(a.x, sc.x, sf.x), 0.f);
                    a.y = fmaxf(fmaf(a.y, sc.y, sf.y), 0.f);
                    a.z = fmaxf(fmaf(a.z, sc.z, sf.z), 0.f);
                    a.w = fmaxf(fmaf(a.w, sc.w, sf.w), 0.f);
                }
                acc[r].x = fmaf(a.w, b3.x, fmaf(a.z, b2.x, fmaf(a.y, b1.x, fmaf(a.x, b0.x, acc[r].x))));
                acc[r].y = fmaf(a.w, b3.y, fmaf(a.z, b2.y, fmaf(a.y, b1.y, fmaf(a.x, b0.y, acc[r].y))));
                acc[r].z = fmaf(a.w, b3.z, fmaf(a.z, b2.z, fmaf(a.y, b1.z, fmaf(a.x, b0.z, acc[r].z))));
                acc[r].w = fmaf(a.w, b3.w, fmaf(a.z, b2.w, fmaf(a.y, b1.w, fmaf(a.x, b0.w, acc[r].w))));
            }
        }
    }

    float4 bv = ((const float4*)bias)[tx];
    float4* out4 = (float4*)out;
    float4 s4 = make_float4(0.f, 0.f, 0.f, 0.f);
    float4 q4 = make_float4(0.f, 0.f, 0.f, 0.f);
#pragma unroll
    for (int r = 0; r < 4; r++) {
        int row = row0 + r;
        if (row < nrows) {
            float4 o;
            o.x = acc[r].x + bv.x; o.y = acc[r].y + bv.y;
            o.z = acc[r].z + bv.z; o.w = acc[r].w + bv.w;
            out4[(size_t)row * D4 + tx] = o;
            s4.x += o.x; s4.y += o.y; s4.z += o.z; s4.w += o.w;
            q4.x = fmaf(o.x, o.x, q4.x); q4.y = fmaf(o.y, o.y, q4.y);
            q4.z = fmaf(o.z, o.z, q4.z); q4.w = fmaf(o.w, o.w, q4.w);
        }
    }

    // block-wide column reduction in (reused) Ws, then one atomic set per block
    __syncthreads();
    float4* red = (float4*)Ws;          // 2 x 256 float4 = 8 KB of the 32 KB
    red[tid] = s4;
    red[256 + tid] = q4;
    __syncthreads();
#pragma unroll
    for (int off = 128; off >= 32; off >>= 1) {
        if (tid < off) {
            float4 a = red[tid], b = red[tid + off];
            a.x += b.x; a.y += b.y; a.z += b.z; a.w += b.w;
            red[tid] = a;
            float4 c = red[256 + tid], d = red[256 + tid + off];
            c.x += d.x; c.y += d.y; c.z += d.z; c.w += d.w;
            red[256 + tid] = c;
        }
        __syncthreads();
    }
    if (tid < 32) {
        float4 s = red[tid], q = red[256 + tid];
        atomicAdd(&sum_out[tid * 4 + 0], s.x);
        atomicAdd(&sum_out[tid * 4 + 1], s.y);
        atomicAdd(&sum_out[tid * 4 + 2], s.z);
        atomicAdd(&sum_out[tid * 4 + 3], s.w);
        atomicAdd(&ssq_out[tid * 4 + 0], q.x);
        atomicAdd(&ssq_out[tid * 4 + 1], q.y);
        atomicAdd(&ssq_out[tid * 4 + 2], q.z);
        atomicAdd(&ssq_out[tid * 4 + 3], q.w);
    }
}

// ---------------------------------------------------------------------------
// Final BN apply (no relu), coefs computed inline from raw sums.
// ---------------------------------------------------------------------------
__global__ __launch_bounds__(256) void apply_final_kernel(
    const float* __restrict__ X, const float* __restrict__ sum2,
    const float* __restrict__ ssq2, const float* __restrict__ gam,
    const float* __restrict__ bet, float* __restrict__ out, int n4)
{
    int i = blockIdx.x * blockDim.x + threadIdx.x;
    if (i >= n4) return;
    int c4 = i & 31;
    float4 sm = ((const float4*)sum2)[c4];
    float4 sq = ((const float4*)ssq2)[c4];
    float4 g  = ((const float4*)gam)[c4];
    float4 b  = ((const float4*)bet)[c4];
    float mux = sm.x * INVN, muy = sm.y * INVN, muz = sm.z * INVN, muw = sm.w * INVN;
    float4 sc, sf;
    sc.x = g.x * rsqrtf(fmaxf(sq.x * INVN - mux * mux, 0.f) + BN_EPS);
    sc.y = g.y * rsqrtf(fmaxf(sq.y * INVN - muy * muy, 0.f) + BN_EPS);
    sc.z = g.z * rsqrtf(fmaxf(sq.z * INVN - muz * muz, 0.f) + BN_EPS);
    sc.w = g.w * rsqrtf(fmaxf(sq.w * INVN - muw * muw, 0.f) + BN_EPS);
    sf.x = fmaf(-mux, sc.x, b.x); sf.y = fmaf(-muy, sc.y, b.y);
    sf.z = fmaf(-muz, sc.z, b.z); sf.w = fmaf(-muw, sc.w, b.w);
    float4 v = ((const float4*)X)[i];
    v.x = fmaf(v.x, sc.x, sf.x);
    v.y = fmaf(v.y, sc.y, sf.y);
    v.z = fmaf(v.z, sc.z, sf.z);
    v.w = fmaf(v.w, sc.w, sf.w);
    ((float4*)out)[i] = v;
}

// ---------------------------------------------------------------------------
extern "C" void kernel_launch(void* const* d_in, const int* in_sizes, int n_in,
                              void* d_out, int out_size, void* d_ws, size_t ws_size,
                              hipStream_t stream)
{
    const int*   x         = (const int*)d_in[0];
    const int*   edge_attr = (const int*)d_in[1];
    const int*   src       = (const int*)d_in[2];
    const int*   dst       = (const int*)d_in[3];
    const float* atom_emb  = (const float*)d_in[4];
    const float* bond_emb  = (const float*)d_in[5];
    const float* W1        = (const float*)d_in[6];
    const float* b1        = (const float*)d_in[7];
    const float* g1        = (const float*)d_in[8];
    const float* be1       = (const float*)d_in[9];
    const float* W2        = (const float*)d_in[10];
    const float* b2        = (const float*)d_in[11];
    const float* gin_eps   = (const float*)d_in[12];
    const float* og        = (const float*)d_in[13];
    const float* ob        = (const float*)d_in[14];
    float* out = (float*)d_out;

    const size_t ND = (size_t)N_NODES * DIM;
    const int NBLK = (N_NODES + 255) / 256;   // 196

    // workspace layout: per-layer stats first (16B alignment preserved)
    // stats layer l: [l*512+0..127]=sum1, +128 ssq1, +256 sum2, +384 ssq2
    float* stats = (float*)d_ws;            // 2048 floats reserved
    float* zagg  = stats + 2048;            // agg output
    float* z2buf = zagg + ND;               // atom output & gemm2 output
    float* z1    = out;                     // gemm1 output aliases d_out
    int* counts   = (int*)(z2buf + ND);
    int* row_ptr  = counts + N_NODES;
    int* cursor   = row_ptr + N_NODES + 1;
    int* esrc     = cursor + N_NODES;
    int* ebond    = esrc + N_EDGES;
    int* incl     = ebond + N_EDGES;
    int* blk_sums = incl + N_NODES;         // NBLK ints

    hipMemsetAsync(counts, 0, N_NODES * sizeof(int), stream);
    hipMemsetAsync(stats, 0, 1536 * sizeof(float), stream);
    atom_kernel<<<(N_NODES + 7) / 8, 256, 0, stream>>>(x, atom_emb, z2buf, N_NODES);
    hist_kernel<<<(N_EDGES + 255) / 256, 256, 0, stream>>>(dst, counts, N_EDGES);
    scan1_kernel<<<NBLK, 256, 0, stream>>>(counts, incl, blk_sums, N_NODES);
    scan2_kernel<<<1, 256, 0, stream>>>(blk_sums, NBLK);
    scan3_kernel<<<NBLK, 256, 0, stream>>>(counts, incl, blk_sums, row_ptr, cursor, N_NODES);
    fill_kernel<<<(N_EDGES + 255) / 256, 256, 0, stream>>>(dst, src, edge_attr, cursor,
                                                           esrc, ebond, N_EDGES);

    const int GGRID = (N_NODES + GROWS - 1) / GROWS;   // 1563
    for (int l = 0; l < NLAYERS; l++) {
        const float* bond_l = bond_emb + (size_t)l * NBOND * BVOC * DIM;
        float* st   = stats + (size_t)l * 512;
        float* sum1 = st,       *ssq1 = st + 128;
        float* sum2 = st + 256, *ssq2 = st + 384;

        if (l == 0) {
            agg_kernel<false><<<(N_NODES + 7) / 8, 256, 0, stream>>>(
                z2buf, row_ptr, esrc, ebond, bond_l, gin_eps + l,
                nullptr, nullptr, nullptr, nullptr, zagg, N_NODES);
        } else {
            float* stp = stats + (size_t)(l - 1) * 512;
            agg_kernel<true><<<(N_NODES + 7) / 8, 256, 0, stream>>>(
                z2buf, row_ptr, esrc, ebond, bond_l, gin_eps + l,
                stp + 256, stp + 384, og + (l - 1) * DIM, ob + (l - 1) * DIM,
                zagg, N_NODES);
        }
        gemm_kernel<false><<<GGRID, 256, 0, stream>>>(
            zagg, W1 + (size_t)l * DIM * DIM, b1 + l * DIM,
            nullptr, nullptr, nullptr, nullptr, sum1, ssq1, z1, N_NODES);
        gemm_kernel<true><<<GGRID, 256, 0, stream>>>(
            z1, W2 + (size_t)l * DIM * DIM, b2 + l * DIM,
            sum1, ssq1, g1 + l * DIM, be1 + l * DIM, sum2, ssq2, z2buf, N_NODES);
    }
    {
        float* stp = stats + (size_t)(NLAYERS - 1) * 512;
        apply_final_kernel<<<((int)(N_NODES * D4) + 255) / 256, 256, 0, stream>>>(
            z2buf, stp + 256, stp + 384, og + (NLAYERS - 1) * DIM,
            ob + (NLAYERS - 1) * DIM, out, N_NODES * D4);
    }
}